// Round 8
// baseline (53.287 us; speedup 1.0000x reference)
//
#include <hip/hip_runtime.h>
#include <hip/hip_fp16.h>
#include <cmath>

#define NBINS   84
#define NFRAMES 256
#define HOP     1024
#define NB      8            // nb_samples * nb_channels
#define KP      960          // padded K (columns of A / rows of B)
#define KPH     (KP/2)       // 480 column pairs (cos,sin)
#define GBLK    278          // number of 1024-sample output blocks
#define MROWS   (GBLK*NB)    // 2224 real rows
#define MPAD    2240         // 35*64
#define SD      23           // d-slices: max ceil(L/1024)

// mega_build regions (blocks of 256 threads)
#define BT_BLOCKS  2048          // 2 blocks per r (480 pairs), 1024 r
#define A_BLOCKS   (2*MPAD)      // 4480: 2 blocks per row
#define S_BLOCKS   92            // 23*1024/256 : S[t] window-energy table
#define ALL_BLOCKS (BT_BLOCKS + A_BLOCKS + S_BLOCKS)

typedef _Float16 f16x8 __attribute__((ext_vector_type(8)));
typedef float    f32x4 __attribute__((ext_vector_type(4)));

struct CqtArgs {
    int   wl[NBINS];            // per-bin window length (descending)
    float omega[NBINS];         // 2*pi*f/SR
    float invL[NBINS];          // 1/wl
    int   Ktot;
    unsigned short ct[KP];      // col -> k | d<<7 | c<<12 ; 0xFFFF = pad
};

// Fused builder: region 0 = Bt (pairwise), region 1 = A (pairwise), region 2 = S[t].
__global__ __launch_bounds__(256)
void mega_build(unsigned short* __restrict__ Am, unsigned short* __restrict__ Bt,
                float* __restrict__ S, const float* __restrict__ X, CqtArgs a) {
    const int blk = blockIdx.x;
    const int tid = threadIdx.x;
    const float TWOPI = 6.28318530717958647692f;

    if (blk < BT_BLOCKS) {
        // ---- Bt[r][2j]=cos(w_k t)*hann, Bt[r][2j+1]=sin(w_k t)*hann; t=1024d+r
        const int r = blk >> 1;
        const int j = (blk & 1) * 256 + tid;
        if (j >= KPH) return;
        unsigned int pack = 0;
        const unsigned short rec = a.ct[2 * j];
        if (rec != 0xFFFF) {
            const int k = rec & 0x7F, d = (rec >> 7) & 0x1F;
            const int t = (d << 10) + r;
            if (t < a.wl[k]) {
                const float tf = (float)t;
                const float w  = 0.5f - 0.5f * cosf(TWOPI * tf * a.invL[k]);
                float s, c;
                sincosf(a.omega[k] * tf, &s, &c);
                pack = (unsigned int)__half_as_ushort(__float2half(c * w))
                     | ((unsigned int)__half_as_ushort(__float2half(s * w)) << 16);
            }
        }
        *(unsigned int*)(Bt + (size_t)r * KP + 2 * j) = pack;
    } else if (blk < BT_BLOCKS + A_BLOCKS) {
        // ---- A[row][2j]=Re X[b,k,g-d], A[row][2j+1]=-Im X[b,k,g-d]; row=(g*8+b)
        const int idx = blk - BT_BLOCKS;
        const int row = idx >> 1;
        const int j   = (idx & 1) * 256 + tid;
        if (j >= KPH) return;
        unsigned int pack = 0;
        const unsigned short rec = a.ct[2 * j];
        if (row < MROWS && rec != 0xFFFF) {
            const int k = rec & 0x7F, d = (rec >> 7) & 0x1F;
            const int g = row >> 3, b = row & 7;
            const int f = g - d;
            if (f >= 0 && f < NFRAMES) {
                const float2 x = *(const float2*)(X + (((size_t)b * NBINS + k) * NFRAMES + f) * 2);
                pack = (unsigned int)__half_as_ushort(__float2half(x.x))
                     | ((unsigned int)__half_as_ushort(__float2half(-x.y)) << 16);
            }
        }
        *(unsigned int*)(Am + (size_t)row * KP + 2 * j) = pack;
    } else {
        // ---- S[t] = sum_k [t < wl_k] hann_k(t)^2 ; wl descending -> prefix, break
        const int t = (blk - BT_BLOCKS - A_BLOCKS) * 256 + tid;   // t < 23552
        float sum = 0.f;
        for (int k = 0; k < NBINS; ++k) {
            if (t >= a.wl[k]) break;
            const float w = 0.5f - 0.5f * cosf(TWOPI * (float)t * a.invL[k]);
            sum += w * w;
        }
        S[t] = sum;
    }
}

// inverse norm for output block-row g at column ncol:
//   norm(g, ncol) = sum_{d=max(0, g-255)}^{min(g, 22)} S[(d<<10) + ncol]
// DIRECT positive-term sum — no prefix-difference (f32 cancellation near signal
// tail turned a ~1e-15 norm into ±1e-6 noise in R7; that was the failure).
__device__ __forceinline__ float inv_norm(const float* __restrict__ S, int g, int ncol) {
    if (g >= GBLK) return 1.0f;                     // padding rows, value unused
    const int lo = (g > NFRAMES - 1) ? (g - (NFRAMES - 1)) : 0;
    const int hi = g < (SD - 1) ? g : (SD - 1);
    float s = 0.f;
    for (int d = lo; d <= hi; ++d) s += S[(d << 10) + ncol];
    return (s > 1e-10f) ? 1.0f / s : 1.0f;
}

// GEMM: C[M=2240][N=1024] = A[M][K=960] * Bt[N][K]^T, f16 in / f32 acc.
// 64x64 tile, 4 waves (2x2), each wave 32x32 via 2x2 mfma_f32_16x16x32_f16.
// LDS [row][kchunk] with chunk-XOR swizzle (T2); next-K global loads overlap MFMA.
__global__ __launch_bounds__(256)
void gemm_icqt(const unsigned short* __restrict__ Am, const unsigned short* __restrict__ Bt,
               const float* __restrict__ S, float* __restrict__ out, int length) {
    __shared__ __align__(16) char lds[16384];
    const int tid = threadIdx.x;
    const int l   = tid & 63;
    const int wid = tid >> 6;
    const int wm  = wid >> 1, wn = wid & 1;
    const int bm  = blockIdx.x, bn = blockIdx.y;

    // staging: 512 16B-chunks per 64x64 f16 tile; thread covers q0=tid, q1=tid+256
    const int q0 = tid,      q1 = tid + 256;
    const int r0 = q0 >> 3,  c0 = q0 & 7, s0 = c0 ^ (r0 & 7);
    const int r1 = q1 >> 3,  c1 = q1 & 7, s1 = c1 ^ (r1 & 7);

    const char* gA = (const char*)Am + (size_t)(bm * 64) * KP * 2;
    const char* gB = (const char*)Bt + (size_t)(bn * 64) * KP * 2;
    const char* gA0 = gA + ((size_t)r0 * KP + s0 * 8) * 2;
    const char* gA1 = gA + ((size_t)r1 * KP + s1 * 8) * 2;
    const char* gB0 = gB + ((size_t)r0 * KP + s0 * 8) * 2;
    const char* gB1 = gB + ((size_t)r1 * KP + s1 * 8) * 2;
    char* lA = lds;
    char* lB = lds + 8192;

    f32x4 acc00 = {0.f,0.f,0.f,0.f}, acc01 = {0.f,0.f,0.f,0.f};
    f32x4 acc10 = {0.f,0.f,0.f,0.f}, acc11 = {0.f,0.f,0.f,0.f};

    f16x8 ra0 = *(const f16x8*)(gA0);
    f16x8 ra1 = *(const f16x8*)(gA1);
    f16x8 rb0 = *(const f16x8*)(gB0);
    f16x8 rb1 = *(const f16x8*)(gB1);

    const int arow0 = wm * 32 + (l & 15), arow1 = arow0 + 16;
    const int brow0 = wn * 32 + (l & 15), brow1 = brow0 + 16;
    const int kq = l >> 4;   // 0..3: k-chunk sub-index

    for (int kk = 0; kk < KP; kk += 64) {
        __syncthreads();                     // previous frag reads complete
        *(f16x8*)(lA + q0 * 16) = ra0;
        *(f16x8*)(lA + q1 * 16) = ra1;
        *(f16x8*)(lB + q0 * 16) = rb0;
        *(f16x8*)(lB + q1 * 16) = rb1;
        __syncthreads();
        if (kk + 64 < KP) {                  // prefetch next K-panel (overlaps MFMA)
            ra0 = *(const f16x8*)(gA0 + (kk + 64) * 2);
            ra1 = *(const f16x8*)(gA1 + (kk + 64) * 2);
            rb0 = *(const f16x8*)(gB0 + (kk + 64) * 2);
            rb1 = *(const f16x8*)(gB1 + (kk + 64) * 2);
        }
#pragma unroll
        for (int ks = 0; ks < 2; ++ks) {
            const int kb = ks * 4 + kq;      // chunk 0..7 within row
            f16x8 a0 = *(const f16x8*)(lA + arow0 * 128 + ((kb ^ (arow0 & 7)) << 4));
            f16x8 a1 = *(const f16x8*)(lA + arow1 * 128 + ((kb ^ (arow1 & 7)) << 4));
            f16x8 b0 = *(const f16x8*)(lB + brow0 * 128 + ((kb ^ (brow0 & 7)) << 4));
            f16x8 b1 = *(const f16x8*)(lB + brow1 * 128 + ((kb ^ (brow1 & 7)) << 4));
            acc00 = __builtin_amdgcn_mfma_f32_16x16x32_f16(a0, b0, acc00, 0, 0, 0);
            acc01 = __builtin_amdgcn_mfma_f32_16x16x32_f16(a0, b1, acc01, 0, 0, 0);
            acc10 = __builtin_amdgcn_mfma_f32_16x16x32_f16(a1, b0, acc10, 0, 0, 0);
            acc11 = __builtin_amdgcn_mfma_f32_16x16x32_f16(a1, b1, acc11, 0, 0, 0);
        }
    }

    // epilogue: C/D layout col=l&15, row=(l>>4)*4+reg. Per lane, the 16 elements
    // span exactly 2 g's (g0, g0+2) x 2 ncols -> 4 inverse-norm values from S.
    const int mbase = bm * 64 + wm * 32;
    const int nbase = bn * 64 + wn * 32;
    const int ncol0 = nbase + (l & 15);
    const int ncol1 = ncol0 + 16;
    const int g0    = (mbase >> 3) + (kq >> 1);
    const float inv00 = inv_norm(S, g0,     ncol0);
    const float inv01 = inv_norm(S, g0,     ncol1);
    const float inv10 = inv_norm(S, g0 + 2, ncol0);
    const float inv11 = inv_norm(S, g0 + 2, ncol1);

#pragma unroll
    for (int mi = 0; mi < 2; ++mi) {
#pragma unroll
        for (int ni = 0; ni < 2; ++ni) {
            f32x4 v = (mi == 0) ? ((ni == 0) ? acc00 : acc01)
                                : ((ni == 0) ? acc10 : acc11);
            const float invv = (mi == 0) ? ((ni == 0) ? inv00 : inv01)
                                         : ((ni == 0) ? inv10 : inv11);
            const int ncol = (ni == 0) ? ncol0 : ncol1;
#pragma unroll
            for (int reg = 0; reg < 4; ++reg) {
                const int mrow = mbase + mi * 16 + kq * 4 + reg;
                if (mrow < MROWS) {
                    const int g = mrow >> 3, b = mrow & 7;
                    const int p = (g << 10) + ncol;
                    if (p < length)
                        out[(size_t)b * length + p] = v[reg] * invv;
                }
            }
        }
    }
}

// Last-resort fallback (ws too small): on-the-fly trig gather.
__global__ void icqt_gather_fallback(const float* __restrict__ X, float* __restrict__ out,
                                     CqtArgs a, int length) {
    const int p = blockIdx.x * blockDim.x + threadIdx.x;
    if (p >= length) return;
    float acc[NB];
#pragma unroll
    for (int b = 0; b < NB; ++b) acc[b] = 0.0f;
    float nrm = 0.0f;
    int fhi = p >> 10;
    if (fhi > NFRAMES - 1) fhi = NFRAMES - 1;
    const float2* X2 = reinterpret_cast<const float2*>(X);
    for (int k = 0; k < NBINS; ++k) {
        const int L = a.wl[k];
        int flo = (p - L + HOP) >> 10;
        if (flo < 0) flo = 0;
        for (int f = flo; f <= fhi; ++f) {
            const int t = p - (f << 10);
            if (t < L) {
                float tf = (float)t;
                float ang = a.omega[k] * tf;
                float s = sinf(ang), c = cosf(ang);
                float w = 0.5f - 0.5f * cosf(6.28318530717958647692f * tf * a.invL[k]);
                float bre = c * w, bim = s * w;
                nrm += w * w;
                const int base = k * NFRAMES + f;
#pragma unroll
                for (int b = 0; b < NB; ++b) {
                    float2 cv = X2[(size_t)b * (NBINS * NFRAMES) + base];
                    acc[b] += cv.x * bre - cv.y * bim;
                }
            }
        }
    }
    const float inv = 1.0f / ((nrm > 1e-10f) ? nrm : 1.0f);
#pragma unroll
    for (int b = 0; b < NB; ++b)
        out[(size_t)b * length + p] = acc[b] * inv;
}

extern "C" void kernel_launch(void* const* d_in, const int* in_sizes, int n_in,
                              void* d_out, int out_size, void* d_ws, size_t ws_size,
                              hipStream_t stream) {
    // Host geometry (deterministic; np.round = banker's via nearbyint)
    CqtArgs a;
    int cb[NBINS];
    const double SR = 44100.0;
    const double Q  = 1.0 / (std::exp2(1.0 / 12.0) - 1.0);
    int Ktot = 0;
    for (int k = 0; k < NBINS; ++k) {
        double f = 32.7 * std::exp2((double)k / 12.0);
        int L = (int)std::nearbyint(Q * SR / f);
        a.wl[k]    = L;
        cb[k]      = Ktot;
        a.omega[k] = (float)(2.0 * 3.14159265358979323846 * f / SR);
        a.invL[k]  = (float)(1.0 / (double)L);
        Ktot += 2 * ((L + 1023) / 1024);
    }
    a.Ktot = Ktot;
    // host-side coltab, compressed: k | d<<7 | c<<12, 0xFFFF = pad
    for (int col = 0; col < KP; ++col) a.ct[col] = 0xFFFF;
    if (Ktot <= KP) {
        for (int k = 0; k < NBINS; ++k) {
            const int D2 = 2 * ((a.wl[k] + 1023) / 1024);
            for (int j = 0; j < D2; ++j)
                a.ct[cb[k] + j] = (unsigned short)(k | ((j >> 1) << 7) | ((j & 1) << 12));
        }
    }

    const int length = out_size / NB;            // 283800
    const float* X = (const float*)d_in[0];
    float* out     = (float*)d_out;

    // ws layout (16B-aligned by construction)
    const size_t offA = 0;
    const size_t szA  = (size_t)MPAD * KP * 2;           // 4,300,800
    const size_t offB = offA + szA;
    const size_t szB  = (size_t)1024 * KP * 2;           // 1,966,080
    const size_t offS = offB + szB;
    const size_t szS  = (size_t)SD * 1024 * 4;           //    94,208
    const size_t need = offS + szS;

    if (Ktot > KP || a.wl[0] > SD * 1024 || ws_size < need) {
        const int blocks = (length + 255) / 256;
        icqt_gather_fallback<<<blocks, 256, 0, stream>>>(X, out, a, length);
        return;
    }

    unsigned short* Am = (unsigned short*)((char*)d_ws + offA);
    unsigned short* Bt = (unsigned short*)((char*)d_ws + offB);
    float*          S  = (float*)((char*)d_ws + offS);

    mega_build<<<dim3(ALL_BLOCKS), 256, 0, stream>>>(Am, Bt, S, X, a);
    gemm_icqt<<<dim3(MPAD / 64, 1024 / 64), 256, 0, stream>>>(Am, Bt, S, out, length);
}